// Round 1
// baseline (70.321 us; speedup 1.0000x reference)
//
#include <hip/hip_runtime.h>

// FastGuidedFilter on MI355X.
// Phase 1: per-channel 5x5 truncated-window box stats -> A, b  (lowres 256x256, 24 channels)
// Phase 2: align_corners bilinear upsample of A,b fused with out = A*x_hr + b (1024x1024)

constexpr int H_LR = 256, W_LR = 256;
constexpr int H_HR = 1024, W_HR = 1024;
constexpr int NC   = 24;          // 8 * 3
constexpr int RAD  = 2;           // kernel_size 5

// ---------------- Phase 1: A,b on the lowres grid ----------------
// block 16x16 -> one 16x16 output tile, 20x20 halo staged in LDS.
__global__ void __launch_bounds__(256) ab_kernel(const float* __restrict__ x,
                                                 const float* __restrict__ y,
                                                 float* __restrict__ A,
                                                 float* __restrict__ B) {
    __shared__ float sx[20][21];  // +1 pad: avoid 2-lane-group bank aliasing on row reads
    __shared__ float sy[20][21];

    const int c  = blockIdx.z;
    const int ti = blockIdx.y * 16;
    const int tj = blockIdx.x * 16;
    const float* __restrict__ xc = x + c * (H_LR * W_LR);
    const float* __restrict__ yc = y + c * (H_LR * W_LR);

    // cooperative halo load (400 elements, 256 threads -> 2 rounds)
    const int t = threadIdx.y * 16 + threadIdx.x;
    for (int idx = t; idx < 20 * 20; idx += 256) {
        const int li = idx / 20, lj = idx - li * 20;
        const int gi = ti + li - RAD, gj = tj + lj - RAD;
        float vx = 0.f, vy = 0.f;
        if (gi >= 0 && gi < H_LR && gj >= 0 && gj < W_LR) {
            vx = xc[gi * W_LR + gj];
            vy = yc[gi * W_LR + gj];
        }
        sx[li][lj] = vx;
        sy[li][lj] = vy;
    }
    __syncthreads();

    const int i = ti + (int)threadIdx.y;
    const int j = tj + (int)threadIdx.x;
    // truncated window bounds (reference's cumsum-diff semantics)
    const int i0 = max(i - RAD, 0), i1 = min(i + RAD, H_LR - 1);
    const int j0 = max(j - RAD, 0), j1 = min(j + RAD, W_LR - 1);

    float sxs = 0.f, sys = 0.f, sxy = 0.f, sxx = 0.f;
    for (int ii = i0; ii <= i1; ++ii) {
        const int li = ii - ti + RAD;
        #pragma unroll 5
        for (int jj = j0; jj <= j1; ++jj) {
            const int lj = jj - tj + RAD;
            const float vx = sx[li][lj];
            const float vy = sy[li][lj];
            sxs += vx;
            sys += vy;
            sxy += vx * vy;
            sxx += vx * vx;
        }
    }
    const float n   = (float)((i1 - i0 + 1) * (j1 - j0 + 1));
    const float inv = 1.0f / n;
    const float mx  = sxs * inv;
    const float my  = sys * inv;
    const float cov = sxy * inv - mx * my;
    const float var = sxx * inv - mx * mx;
    const float a   = cov / (var + 1e-8f);
    const float b   = my - a * mx;

    const int o = c * (H_LR * W_LR) + i * W_LR + j;
    A[o] = a;
    B[o] = b;
}

// ---------------- Phase 2: bilinear upsample + apply ----------------
__global__ void __launch_bounds__(256) up_kernel(const float* __restrict__ A,
                                                 const float* __restrict__ B,
                                                 const float* __restrict__ xhr,
                                                 float* __restrict__ out) {
    const int idx = blockIdx.x * 256 + (int)threadIdx.x;
    // idx -> (c, i, j); W_HR = 1024, H_HR = 1024 are powers of two
    const int j = idx & (W_HR - 1);
    const int i = (idx >> 10) & (H_HR - 1);
    const int c = idx >> 20;

    const float sc = (float)(H_LR - 1) / (float)(H_HR - 1);  // 255/1023
    const float fy = (float)i * sc;
    const float fx = (float)j * sc;
    const int y0 = (int)fy;              // fy >= 0, trunc == floor
    const int x0 = (int)fx;
    const float wy = fy - (float)y0;
    const float wx = fx - (float)x0;
    const int y1 = min(y0 + 1, H_LR - 1);
    const int x1 = min(x0 + 1, W_LR - 1);

    const int base = c * (H_LR * W_LR);
    const int r0 = base + y0 * W_LR;
    const int r1 = base + y1 * W_LR;

    const float a00 = A[r0 + x0], a01 = A[r0 + x1];
    const float a10 = A[r1 + x0], a11 = A[r1 + x1];
    const float b00 = B[r0 + x0], b01 = B[r0 + x1];
    const float b10 = B[r1 + x0], b11 = B[r1 + x1];

    // interpolate over y first (matches reference order), then x
    const float a_l = a00 * (1.f - wy) + a10 * wy;
    const float a_r = a01 * (1.f - wy) + a11 * wy;
    const float b_l = b00 * (1.f - wy) + b10 * wy;
    const float b_r = b01 * (1.f - wy) + b11 * wy;
    const float a = a_l * (1.f - wx) + a_r * wx;
    const float b = b_l * (1.f - wx) + b_r * wx;

    out[idx] = a * xhr[idx] + b;
}

extern "C" void kernel_launch(void* const* d_in, const int* in_sizes, int n_in,
                              void* d_out, int out_size, void* d_ws, size_t ws_size,
                              hipStream_t stream) {
    const float* x_lr = (const float*)d_in[0];  // input_lowres  [8,3,256,256]
    const float* y_lr = (const float*)d_in[1];  // guide_lowres  [8,3,256,256]
    const float* x_hr = (const float*)d_in[2];  // input_highres [8,3,1024,1024]
    float* out = (float*)d_out;

    float* A = (float*)d_ws;                    // 24*256*256 floats
    float* B = A + NC * H_LR * W_LR;            // 24*256*256 floats (total 48 MB of ws)

    dim3 b1(16, 16, 1);
    dim3 g1(W_LR / 16, H_LR / 16, NC);
    ab_kernel<<<g1, b1, 0, stream>>>(x_lr, y_lr, A, B);

    const int total = NC * H_HR * W_HR;         // 25,165,824
    up_kernel<<<total / 256, 256, 0, stream>>>(A, B, x_hr, out);
}

// Round 2
// 66.009 us; speedup vs baseline: 1.0653x; 1.0653x over previous
//
#include <hip/hip_runtime.h>

// FastGuidedFilter on MI355X.
// Phase 1: per-channel 5x5 truncated-window box stats -> A, b  (lowres 256x256, 24 channels)
// Phase 2: per-(channel,row) blocks: y-interp A,b rows into LDS once, then
//          float4-vectorized horizontal interp fused with out = A*x_hr + b.

constexpr int H_LR = 256, W_LR = 256;
constexpr int H_HR = 1024, W_HR = 1024;
constexpr int NC   = 24;          // 8 * 3
constexpr int RAD  = 2;           // kernel_size 5

// ---------------- Phase 1: A,b on the lowres grid ----------------
// block 16x16 -> one 16x16 output tile, 20x20 halo staged in LDS.
__global__ void __launch_bounds__(256) ab_kernel(const float* __restrict__ x,
                                                 const float* __restrict__ y,
                                                 float* __restrict__ A,
                                                 float* __restrict__ B) {
    __shared__ float sx[20][21];
    __shared__ float sy[20][21];

    const int c  = blockIdx.z;
    const int ti = blockIdx.y * 16;
    const int tj = blockIdx.x * 16;
    const float* __restrict__ xc = x + c * (H_LR * W_LR);
    const float* __restrict__ yc = y + c * (H_LR * W_LR);

    const int t = threadIdx.y * 16 + threadIdx.x;
    for (int idx = t; idx < 20 * 20; idx += 256) {
        const int li = idx / 20, lj = idx - li * 20;
        const int gi = ti + li - RAD, gj = tj + lj - RAD;
        float vx = 0.f, vy = 0.f;
        if (gi >= 0 && gi < H_LR && gj >= 0 && gj < W_LR) {
            vx = xc[gi * W_LR + gj];
            vy = yc[gi * W_LR + gj];
        }
        sx[li][lj] = vx;
        sy[li][lj] = vy;
    }
    __syncthreads();

    const int i = ti + (int)threadIdx.y;
    const int j = tj + (int)threadIdx.x;
    const int i0 = max(i - RAD, 0), i1 = min(i + RAD, H_LR - 1);
    const int j0 = max(j - RAD, 0), j1 = min(j + RAD, W_LR - 1);

    float sxs = 0.f, sys = 0.f, sxy = 0.f, sxx = 0.f;
    for (int ii = i0; ii <= i1; ++ii) {
        const int li = ii - ti + RAD;
        #pragma unroll 5
        for (int jj = j0; jj <= j1; ++jj) {
            const int lj = jj - tj + RAD;
            const float vx = sx[li][lj];
            const float vy = sy[li][lj];
            sxs += vx;
            sys += vy;
            sxy += vx * vy;
            sxx += vx * vx;
        }
    }
    const float n   = (float)((i1 - i0 + 1) * (j1 - j0 + 1));
    const float inv = 1.0f / n;
    const float mx  = sxs * inv;
    const float my  = sys * inv;
    const float cov = sxy * inv - mx * my;
    const float var = sxx * inv - mx * mx;
    const float a   = cov / (var + 1e-8f);
    const float b   = my - a * mx;

    const int o = c * (H_LR * W_LR) + i * W_LR + j;
    A[o] = a;
    B[o] = b;
}

// ---------------- Phase 2: row-staged bilinear + apply ----------------
// grid = (H_HR, NC); 256 threads/block; each thread does 4 consecutive pixels.
__global__ void __launch_bounds__(256) up_kernel(const float* __restrict__ A,
                                                 const float* __restrict__ B,
                                                 const float* __restrict__ xhr,
                                                 float* __restrict__ out) {
    __shared__ float ar[W_LR];
    __shared__ float br[W_LR];

    const int i = blockIdx.x;          // highres row
    const int c = blockIdx.y;          // channel
    const int t = (int)threadIdx.x;

    const float sc = (float)(H_LR - 1) / (float)(H_HR - 1);  // 255/1023

    // ---- y-interp of the two needed lowres rows into LDS (one column/thread)
    const float fy = (float)i * sc;
    const int   y0 = (int)fy;
    const float wy = fy - (float)y0;
    const int   y1 = min(y0 + 1, H_LR - 1);
    {
        const int base = c * (H_LR * W_LR);
        const float a0 = A[base + y0 * W_LR + t];
        const float a1 = A[base + y1 * W_LR + t];
        const float b0 = B[base + y0 * W_LR + t];
        const float b1 = B[base + y1 * W_LR + t];
        ar[t] = a0 * (1.f - wy) + a1 * wy;   // same formula order as reference
        br[t] = b0 * (1.f - wy) + b1 * wy;
    }
    __syncthreads();

    // ---- horizontal interp, 4 px/thread, float4 streaming
    const size_t rowoff = (size_t)c * (H_HR * W_HR) + (size_t)i * W_HR;
    const int j0 = t * 4;

    const float4 xv = *reinterpret_cast<const float4*>(xhr + rowoff + j0);
    float4 ov;
    float* ovp = &ov.x;
    const float* xvp = &xv.x;
    #pragma unroll
    for (int k = 0; k < 4; ++k) {
        const int   j  = j0 + k;
        const float fx = (float)j * sc;
        const int   x0 = (int)fx;
        const float wx = fx - (float)x0;
        const int   x1 = min(x0 + 1, W_LR - 1);
        const float a  = ar[x0] * (1.f - wx) + ar[x1] * wx;
        const float b  = br[x0] * (1.f - wx) + br[x1] * wx;
        ovp[k] = a * xvp[k] + b;
    }
    *reinterpret_cast<float4*>(out + rowoff + j0) = ov;
}

extern "C" void kernel_launch(void* const* d_in, const int* in_sizes, int n_in,
                              void* d_out, int out_size, void* d_ws, size_t ws_size,
                              hipStream_t stream) {
    const float* x_lr = (const float*)d_in[0];  // input_lowres  [8,3,256,256]
    const float* y_lr = (const float*)d_in[1];  // guide_lowres  [8,3,256,256]
    const float* x_hr = (const float*)d_in[2];  // input_highres [8,3,1024,1024]
    float* out = (float*)d_out;

    float* A = (float*)d_ws;                    // 24*256*256 floats
    float* B = A + NC * H_LR * W_LR;

    dim3 b1(16, 16, 1);
    dim3 g1(W_LR / 16, H_LR / 16, NC);
    ab_kernel<<<g1, b1, 0, stream>>>(x_lr, y_lr, A, B);

    dim3 g2(H_HR, NC, 1);
    up_kernel<<<g2, 256, 0, stream>>>(A, B, x_hr, out);
}

// Round 3
// 51.082 us; speedup vs baseline: 1.3766x; 1.2922x over previous
//
#include <hip/hip_runtime.h>

// FastGuidedFilter, fully fused single kernel.
// Block = (channel, group of 4 highres rows). 256 threads.
//  1. issue the 4 highres-row float4 loads (latency hidden under steps 2-4)
//  2. stage 7 lowres rows of x,y into LDS (zero-filled outside image)
//  3. compute A,b for the 3 lowres rows this group can touch
//     (separable: vertical truncated-window column sums, then horizontal window)
//  4. x-interp A,b per highres column into registers (shared by all 4 rows)
//  5. per hr row: 3-weight y-interp + out = A*x_hr + b, nontemporal store

typedef float f4 __attribute__((ext_vector_type(4)));

constexpr int H_LR = 256, W_LR = 256;
constexpr int H_HR = 1024, W_HR = 1024;
constexpr int NC   = 24;       // 8 * 3
constexpr int RAD  = 2;        // kernel_size 5
constexpr int RPB  = 4;        // highres rows per block

__global__ void __launch_bounds__(256) fgf_fused(const float* __restrict__ xlr,
                                                 const float* __restrict__ ylr,
                                                 const float* __restrict__ xhr,
                                                 float* __restrict__ out) {
    __shared__ float sx[7][W_LR];
    __shared__ float sy[7][W_LR];
    __shared__ float c0[W_LR], c1[W_LR], c2[W_LR], c3[W_LR];  // col sums: x, y, xy, xx
    __shared__ float sA[3][W_LR], sB[3][W_LR];

    const int c  = blockIdx.y;
    const int i0 = blockIdx.x * RPB;
    const int t  = (int)threadIdx.x;
    const float sc = (float)(H_LR - 1) / (float)(H_HR - 1);   // 255/1023

    // ---- 1. issue highres loads early (4 rows x 4 px/thread)
    const size_t hrbase = ((size_t)c << 20) + (size_t)i0 * W_HR + t * 4;
    const f4 xv0 = *(const f4*)(xhr + hrbase);
    const f4 xv1 = *(const f4*)(xhr + hrbase + W_HR);
    const f4 xv2 = *(const f4*)(xhr + hrbase + 2 * W_HR);
    const f4 xv3 = *(const f4*)(xhr + hrbase + 3 * W_HR);

    const int y0min = (int)((float)i0 * sc);   // floor; fy >= 0

    // ---- 2. stage lowres rows y0min-2 .. y0min+4 (zero outside image)
    const int lrbase = c * (H_LR * W_LR);
    for (int idx = t; idx < 7 * 64; idx += 256) {
        const int lr = idx >> 6;          // local row 0..6
        const int q  = idx & 63;          // float4 column
        const int gr = y0min - 2 + lr;
        f4 vx = {0.f, 0.f, 0.f, 0.f};
        f4 vy = {0.f, 0.f, 0.f, 0.f};
        if (gr >= 0 && gr < H_LR) {
            vx = *(const f4*)(xlr + lrbase + gr * W_LR + q * 4);
            vy = *(const f4*)(ylr + lrbase + gr * W_LR + q * 4);
        }
        *(f4*)&sx[lr][q * 4] = vx;
        *(f4*)&sy[lr][q * 4] = vy;
    }
    __syncthreads();

    // ---- 3. A,b for lowres rows y0min .. y0min+2 (clamped; dups harmless)
    for (int rr = 0; rr < 3; ++rr) {
        const int r   = min(y0min + rr, H_LR - 1);
        const int ri0 = max(r - RAD, 0), ri1 = min(r + RAD, H_LR - 1);
        float cx = 0.f, cy = 0.f, cxy = 0.f, cxx = 0.f;
        for (int ii = ri0; ii <= ri1; ++ii) {
            const int l = ii - (y0min - 2);           // 0..6, always staged
            const float vx = sx[l][t];
            const float vy = sy[l][t];
            cx += vx; cy += vy; cxy += vx * vy; cxx += vx * vx;
        }
        c0[t] = cx; c1[t] = cy; c2[t] = cxy; c3[t] = cxx;
        __syncthreads();
        const int j0 = max(t - RAD, 0), j1 = min(t + RAD, W_LR - 1);
        float sxs = 0.f, sys = 0.f, sxy = 0.f, sxx = 0.f;
        for (int jj = j0; jj <= j1; ++jj) {
            sxs += c0[jj]; sys += c1[jj]; sxy += c2[jj]; sxx += c3[jj];
        }
        const float inv = 1.0f / (float)((ri1 - ri0 + 1) * (j1 - j0 + 1));
        const float mx  = sxs * inv;
        const float my  = sys * inv;
        const float cov = sxy * inv - mx * my;
        const float var = sxx * inv - mx * mx;
        const float a   = cov / (var + 1e-8f);
        sA[rr][t] = a;
        sB[rr][t] = my - a * mx;
        __syncthreads();   // also protects c0..c3 reuse next iteration
    }

    // ---- 4. x-interp per highres column (4 cols/thread), all 3 lr rows.
    //         Static indices only (runtime-indexed reg arrays -> scratch).
    float ax0[4], ax1[4], ax2[4], bx0[4], bx1[4], bx2[4];
    #pragma unroll
    for (int m = 0; m < 4; ++m) {
        const int   j   = t * 4 + m;
        const float fx  = (float)j * sc;
        const int   x0  = (int)fx;
        const float wx  = fx - (float)x0;
        const int   x1  = min(x0 + 1, W_LR - 1);
        const float wx0 = 1.f - wx;
        ax0[m] = sA[0][x0] * wx0 + sA[0][x1] * wx;
        ax1[m] = sA[1][x0] * wx0 + sA[1][x1] * wx;
        ax2[m] = sA[2][x0] * wx0 + sA[2][x1] * wx;
        bx0[m] = sB[0][x0] * wx0 + sB[0][x1] * wx;
        bx1[m] = sB[1][x0] * wx0 + sB[1][x1] * wx;
        bx2[m] = sB[2][x0] * wx0 + sB[2][x1] * wx;
    }

    // ---- 5. per hr row: 3-weight y-interp (no runtime reg indexing) + apply
    #pragma unroll
    for (int k = 0; k < RPB; ++k) {
        const int   i   = i0 + k;
        const float fy  = (float)i * sc;
        const int   yy0 = (int)fy;
        const float wy  = fy - (float)yy0;
        const int   l0  = yy0 - y0min;                       // 0 or 1
        const int   l1  = min(yy0 + 1, H_LR - 1) - y0min;    // 0..2
        const float w0  = (l0 == 0 ? 1.f - wy : 0.f) + (l1 == 0 ? wy : 0.f);
        const float w1  = (l0 == 1 ? 1.f - wy : 0.f) + (l1 == 1 ? wy : 0.f);
        const float w2  = (l1 == 2 ? wy : 0.f);

        const f4 xvk = (k == 0) ? xv0 : (k == 1) ? xv1 : (k == 2) ? xv2 : xv3;
        f4 ov;
        #pragma unroll
        for (int m = 0; m < 4; ++m) {
            const float a = ax0[m] * w0 + ax1[m] * w1 + ax2[m] * w2;
            const float b = bx0[m] * w0 + bx1[m] * w1 + bx2[m] * w2;
            ov[m] = a * xvk[m] + b;
        }
        __builtin_nontemporal_store(ov, (f4*)(out + hrbase + (size_t)k * W_HR));
    }
}

extern "C" void kernel_launch(void* const* d_in, const int* in_sizes, int n_in,
                              void* d_out, int out_size, void* d_ws, size_t ws_size,
                              hipStream_t stream) {
    const float* x_lr = (const float*)d_in[0];  // input_lowres  [8,3,256,256]
    const float* y_lr = (const float*)d_in[1];  // guide_lowres  [8,3,256,256]
    const float* x_hr = (const float*)d_in[2];  // input_highres [8,3,1024,1024]
    float* out = (float*)d_out;

    dim3 grid(H_HR / RPB, NC, 1);               // 256 x 24 = 6144 blocks
    fgf_fused<<<grid, 256, 0, stream>>>(x_lr, y_lr, x_hr, out);
}

// Round 4
// 42.623 us; speedup vs baseline: 1.6499x; 1.1985x over previous
//
#include <hip/hip_runtime.h>

// FastGuidedFilter, fully fused, 8 highres rows per block.
// Per block (channel, 8 hr rows):
//  1. stage 8 lowres rows of x,y in LDS (zero outside image -> all windows static)
//  2. per-thread column: 16 stride-1 LDS reads -> 4 vertical window sums in regs
//     -> one float4 {sx,sy,sxy,sxx} col-sum per A/b row into zero-padded LDS
//  3. horizontal: 5 ds_read_b128 taps per row -> stats -> A,b (4 rows) in LDS
//  4. x-interp A,b per hr column into registers (static indices only)
//  5. per hr row: 4-weight y-interp + out = A*x_hr + b, nontemporal store
// LDS: stage region (16 KB) aliased with col-sum region (16.6 KB) + A/B (8 KB)
//      = 24.8 KB -> 6 blocks/CU. 4 barriers per 8 hr rows.

typedef float f4 __attribute__((ext_vector_type(4)));

constexpr int H_LR = 256, W_LR = 256;
constexpr int H_HR = 1024, W_HR = 1024;
constexpr int NC   = 24;       // 8 * 3
constexpr int RAD  = 2;        // kernel_size 5
constexpr int RPB  = 8;        // highres rows per block

constexpr int CS_W    = W_LR + 4;            // 260: zero-padded col-sum width
constexpr int CS_BYTES = 4 * CS_W * 4 * 4;   // 16640
constexpr int AB_OFF  = CS_BYTES;            // 16-aligned (1040*16)

__global__ void __launch_bounds__(256) fgf_fused(const float* __restrict__ xlr,
                                                 const float* __restrict__ ylr,
                                                 const float* __restrict__ xhr,
                                                 float* __restrict__ out) {
    __shared__ __align__(16) char lds[CS_BYTES + 2 * 4 * W_LR * 4];  // 24832 B
    auto sx = reinterpret_cast<float(*)[W_LR]>(lds);                 // [8][256]
    auto sy = reinterpret_cast<float(*)[W_LR]>(lds + 8 * W_LR * 4);  // [8][256]
    auto cs = reinterpret_cast<float(*)[CS_W][4]>(lds);              // [4][260][4]
    auto ab = reinterpret_cast<float(*)[W_LR][2]>(lds + AB_OFF);     // [4][256][2]

    const int c  = blockIdx.y;
    const int i0 = blockIdx.x * RPB;
    const int t  = (int)threadIdx.x;
    const float scale = (float)(H_LR - 1) / (float)(H_HR - 1);       // 255/1023

    const int y0min = (int)((float)i0 * scale);                      // floor, >= 0

    // ---- 1. stage lowres rows y0min-2 .. y0min+5 (zero outside image)
    const int lrbase = c * (H_LR * W_LR);
    #pragma unroll
    for (int half = 0; half < 2; ++half) {
        const int idx = half * 256 + t;            // 0..511
        const int lr = idx >> 6, q = idx & 63;
        const int gr = y0min - 2 + lr;
        f4 vx = {0.f, 0.f, 0.f, 0.f};
        f4 vy = {0.f, 0.f, 0.f, 0.f};
        if (gr >= 0 && gr < H_LR) {
            vx = *(const f4*)(xlr + lrbase + gr * W_LR + q * 4);
            vy = *(const f4*)(ylr + lrbase + gr * W_LR + q * 4);
        }
        *(f4*)&sx[lr][q * 4] = vx;
        *(f4*)&sy[lr][q * 4] = vy;
    }
    __syncthreads();

    // ---- 2. vertical window sums (registers), column t
    float vx[8], vy[8];
    #pragma unroll
    for (int l = 0; l < 8; ++l) { vx[l] = sx[l][t]; vy[l] = sy[l][t]; }
    __syncthreads();                               // staging reads done; cs may alias

    #pragma unroll
    for (int rr = 0; rr < 4; ++rr) {               // A/b row y0min+rr (may be >255: unused)
        float a = 0.f, b = 0.f, cxy = 0.f, cxx = 0.f;
        #pragma unroll
        for (int l = rr; l < rr + 5; ++l) {        // static after unroll
            a += vx[l]; b += vy[l]; cxy += vx[l] * vy[l]; cxx += vx[l] * vx[l];
        }
        f4 v = {a, b, cxy, cxx};
        *(f4*)&cs[rr][t + 2][0] = v;
    }
    if (t < 2) {                                   // zero-pad columns
        const f4 z = {0.f, 0.f, 0.f, 0.f};
        #pragma unroll
        for (int rr = 0; rr < 4; ++rr) {
            *(f4*)&cs[rr][t][0] = z;
            *(f4*)&cs[rr][t + W_LR + 2][0] = z;
        }
    }
    __syncthreads();

    // ---- 3. horizontal 5-tap + stats -> A,b
    const int hcnt = min(t + RAD, W_LR - 1) - max(t - RAD, 0) + 1;
    #pragma unroll
    for (int rr = 0; rr < 4; ++rr) {
        f4 s = {0.f, 0.f, 0.f, 0.f};
        #pragma unroll
        for (int d = 0; d < 5; ++d) s += *(const f4*)&cs[rr][t + d][0];
        const int r  = y0min + rr;                 // may exceed 255; vcnt stays >=1
        const int v0 = max(r - RAD, 0), v1 = min(r + RAD, H_LR - 1);
        const float inv = 1.0f / (float)((v1 - v0 + 1) * hcnt);
        const float mx  = s.x * inv;
        const float my  = s.y * inv;
        const float cov = s.z * inv - mx * my;
        const float var = s.w * inv - mx * mx;
        const float a   = cov / (var + 1e-8f);
        ab[rr][t][0] = a;
        ab[rr][t][1] = my - a * mx;
    }
    __syncthreads();

    // ---- 4. x-interp per hr column (4 cols/thread), all 4 A/b rows
    float ax[4][4], bx[4][4];                      // [rr][m], static indices only
    #pragma unroll
    for (int m = 0; m < 4; ++m) {
        const int   j   = t * 4 + m;
        const float fx  = (float)j * scale;
        const int   x0  = (int)fx;
        const float wx  = fx - (float)x0;
        const int   x1  = min(x0 + 1, W_LR - 1);
        const float wx0 = 1.f - wx;
        #pragma unroll
        for (int rr = 0; rr < 4; ++rr) {
            ax[rr][m] = ab[rr][x0][0] * wx0 + ab[rr][x1][0] * wx;
            bx[rr][m] = ab[rr][x0][1] * wx0 + ab[rr][x1][1] * wx;
        }
    }

    // ---- 5. per hr row: 4-weight y-interp + apply
    const size_t hrbase = ((size_t)c << 20) + (size_t)i0 * W_HR + t * 4;
    #pragma unroll
    for (int k = 0; k < RPB; ++k) {
        const int   i   = i0 + k;
        const float fy  = (float)i * scale;
        const int   yy0 = (int)fy;
        const float wy  = fy - (float)yy0;
        const int   l0  = yy0 - y0min;                       // 0..2
        const int   l1  = min(yy0 + 1, H_LR - 1) - y0min;    // 0..3
        const float w0  = (l0 == 0 ? 1.f - wy : 0.f) + (l1 == 0 ? wy : 0.f);
        const float w1  = (l0 == 1 ? 1.f - wy : 0.f) + (l1 == 1 ? wy : 0.f);
        const float w2  = (l0 == 2 ? 1.f - wy : 0.f) + (l1 == 2 ? wy : 0.f);
        const float w3  = (l1 == 3 ? wy : 0.f);

        const f4 xv = *(const f4*)(xhr + hrbase + (size_t)k * W_HR);
        f4 ov;
        #pragma unroll
        for (int m = 0; m < 4; ++m) {
            const float a = ax[0][m] * w0 + ax[1][m] * w1 + ax[2][m] * w2 + ax[3][m] * w3;
            const float b = bx[0][m] * w0 + bx[1][m] * w1 + bx[2][m] * w2 + bx[3][m] * w3;
            ov[m] = a * xv[m] + b;
        }
        __builtin_nontemporal_store(ov, (f4*)(out + hrbase + (size_t)k * W_HR));
    }
}

extern "C" void kernel_launch(void* const* d_in, const int* in_sizes, int n_in,
                              void* d_out, int out_size, void* d_ws, size_t ws_size,
                              hipStream_t stream) {
    const float* x_lr = (const float*)d_in[0];  // input_lowres  [8,3,256,256]
    const float* y_lr = (const float*)d_in[1];  // guide_lowres  [8,3,256,256]
    const float* x_hr = (const float*)d_in[2];  // input_highres [8,3,1024,1024]
    float* out = (float*)d_out;

    dim3 grid(H_HR / RPB, NC, 1);               // 128 x 24 = 3072 blocks
    fgf_fused<<<grid, 256, 0, stream>>>(x_lr, y_lr, x_hr, out);
}